// Round 4
// baseline (1503.229 us; speedup 1.0000x reference)
//
#include <hip/hip_runtime.h>
#include <hip/hip_bf16.h>
#include <math.h>

typedef __hip_bfloat16 bf16;

#define S     64
#define NSUB  1024
#define ESUB  16384
#define NG    65536
#define EG    1048576
#define NH    128
#define KSEL  512

__device__ __forceinline__ bool isF32(const int* __restrict__ fl) {
    // fl[0]=count of 0xFF-exponent halves, fl[1]=count of exact-zero halves (of 2M scanned)
    return fl[0] > 64 || fl[1] > 500000;
}
__device__ __forceinline__ float ldIn(const void* __restrict__ p, size_t i, bool f32) {
    return f32 ? ((const float*)p)[i] : __bfloat162float(((const bf16*)p)[i]);
}

// ---------------- runtime input-dtype probe ----------------
__global__ void k_detect(const unsigned short* __restrict__ sx, int* __restrict__ fl) {
    int i = blockIdx.x * 256 + threadIdx.x;          // 8192 blocks -> 2M halves
    unsigned short h = sx[i];
    int nan = ((h & 0x7F80) == 0x7F80) ? 1 : 0;      // bf16 exp==0xFF pattern
    int zer = (h == 0) ? 1 : 0;
    for (int o = 32; o > 0; o >>= 1) { nan += __shfl_xor(nan, o, 64); zer += __shfl_xor(zer, o, 64); }
    if ((threadIdx.x & 63) == 0) { if (nan) atomicAdd(&fl[0], nan); if (zer) atomicAdd(&fl[1], zer); }
}

// ---------------- CSR build (per-subgraph) ----------------
__global__ void k_count_sub(const int* __restrict__ sei, int* __restrict__ cnt) {
    int e = blockIdx.x * 256 + threadIdx.x;          // < S*ESUB
    int s = e >> 14, el = e & (ESUB - 1);
    int dst = sei[s * 2 * ESUB + ESUB + el];
    atomicAdd(&cnt[s * NSUB + dst], 1);
}

__global__ __launch_bounds__(1024) void k_scan_sub(const int* __restrict__ cnt,
        int* __restrict__ rowptr, int* __restrict__ cur, float* __restrict__ dinv) {
    __shared__ int sh[1024];
    int s = blockIdx.x, t = threadIdx.x;
    int v = cnt[s * NSUB + t];
    sh[t] = v;
    __syncthreads();
    for (int off = 1; off < 1024; off <<= 1) {
        int add = (t >= off) ? sh[t - off] : 0;
        __syncthreads();
        sh[t] += add;
        __syncthreads();
    }
    int incl = sh[t];
    rowptr[s * (NSUB + 1) + t] = incl - v;
    cur[s * NSUB + t] = incl - v;
    dinv[s * NSUB + t] = rsqrtf((float)(v + 1));     // deg = indeg + 1 (self loop)
    if (t == 1023) rowptr[s * (NSUB + 1) + NSUB] = incl;
}

__global__ void k_fill_sub(const int* __restrict__ sei, int* __restrict__ cur,
                           int* __restrict__ col) {
    int e = blockIdx.x * 256 + threadIdx.x;
    int s = e >> 14, el = e & (ESUB - 1);
    int src = sei[s * 2 * ESUB + el];
    int dst = sei[s * 2 * ESUB + ESUB + el];
    int p = atomicAdd(&cur[s * NSUB + dst], 1);
    col[s * ESUB + p] = src;
}

// ---------------- tiled matmul: Y[M,NCOL] = X[M,KDIM] @ W[KDIM,NCOL] ----------------
template<int KDIM, int NCOL>
__global__ __launch_bounds__(256) void k_matmul(const void* __restrict__ X,
        const void* __restrict__ W, float* __restrict__ Y, const int* __restrict__ fl,
        int xExt) {
    __shared__ float As[16][72];   // [k][row]
    __shared__ float Bs[16][68];   // [k][col]
    bool f32 = isF32(fl);
    bool xf32 = xExt ? f32 : true;
    int t = threadIdx.x;
    int row0 = blockIdx.x * 64;
    int col0 = blockIdx.y * 64;
    int tr = t >> 4, tc = t & 15;
    float acc[4][4] = {};
    for (int k0 = 0; k0 < KDIM; k0 += 16) {
        for (int i = t; i < 1024; i += 256) {
            int r = i >> 4, k = i & 15;
            As[k][r] = ldIn(X, (size_t)(row0 + r) * KDIM + k0 + k, xf32);
        }
        for (int i = t; i < 1024; i += 256) {
            int k = i >> 6, c = i & 63;
            Bs[k][c] = ldIn(W, (size_t)(k0 + k) * NCOL + col0 + c, f32);
        }
        __syncthreads();
        #pragma unroll
        for (int k = 0; k < 16; k++) {
            float a0 = As[k][tr * 4 + 0], a1 = As[k][tr * 4 + 1];
            float a2 = As[k][tr * 4 + 2], a3 = As[k][tr * 4 + 3];
            float b0 = Bs[k][tc * 4 + 0], b1 = Bs[k][tc * 4 + 1];
            float b2 = Bs[k][tc * 4 + 2], b3 = Bs[k][tc * 4 + 3];
            acc[0][0] += a0 * b0; acc[0][1] += a0 * b1; acc[0][2] += a0 * b2; acc[0][3] += a0 * b3;
            acc[1][0] += a1 * b0; acc[1][1] += a1 * b1; acc[1][2] += a1 * b2; acc[1][3] += a1 * b3;
            acc[2][0] += a2 * b0; acc[2][1] += a2 * b1; acc[2][2] += a2 * b2; acc[2][3] += a2 * b3;
            acc[3][0] += a3 * b0; acc[3][1] += a3 * b1; acc[3][2] += a3 * b2; acc[3][3] += a3 * b3;
        }
        __syncthreads();
    }
    #pragma unroll
    for (int i = 0; i < 4; i++)
        #pragma unroll
        for (int j = 0; j < 4; j++)
            Y[(size_t)(row0 + tr * 4 + i) * NCOL + col0 + tc * 4 + j] = acc[i][j];
}

// ---------------- GCN aggregate (128 feats) + self + bias + relu ----------------
__global__ void k_agg128(const float* __restrict__ h, const float* __restrict__ dinv,
                         const int* __restrict__ rowptr, const int* __restrict__ col,
                         const void* __restrict__ bias, float* __restrict__ out,
                         const int* __restrict__ fl) {
    bool f32 = isF32(fl);
    int t = threadIdx.x;
    int node = blockIdx.x * 2 + (t >> 7);            // 0..65535
    int f = t & 127;
    int s = node >> 10, nl = node & (NSUB - 1);
    const int* rp = rowptr + s * (NSUB + 1);
    int st = rp[nl], en = rp[nl + 1];
    const int* cl = col + s * ESUB;
    const float* dv = dinv + s * NSUB;
    float acc = 0.f;
    for (int p = st; p < en; p++) {
        int src = cl[p];
        acc += h[((size_t)(s * NSUB + src)) * NH + f] * dv[src];
    }
    float dn = dv[nl];
    float v = acc * dn + h[(size_t)node * NH + f] * dn * dn + ldIn(bias, f, f32);
    out[(size_t)node * NH + f] = fmaxf(v, 0.f);
}

// ---------------- scorer: h = x1 @ Wp ----------------
__global__ void k_score_h(const float* __restrict__ x1, const void* __restrict__ Wp,
                          float* __restrict__ sh, const int* __restrict__ fl) {
    bool f32 = isF32(fl);
    int t = threadIdx.x;
    int n = blockIdx.x * 4 + (t >> 6);
    int l = t & 63;
    float p = x1[(size_t)n * NH + l] * ldIn(Wp, l, f32)
            + x1[(size_t)n * NH + 64 + l] * ldIn(Wp, 64 + l, f32);
    for (int o = 32; o > 0; o >>= 1) p += __shfl_xor(p, o, 64);
    if (l == 0) sh[n] = p;
}

__global__ void k_score_agg(const float* __restrict__ sh, const float* __restrict__ dinv,
                            const int* __restrict__ rowptr, const int* __restrict__ col,
                            const void* __restrict__ bp, float* __restrict__ score,
                            const int* __restrict__ fl) {
    bool f32 = isF32(fl);
    int n = blockIdx.x * 256 + threadIdx.x;          // 0..65535
    int s = n >> 10, nl = n & (NSUB - 1);
    const int* rp = rowptr + s * (NSUB + 1);
    const int* cl = col + s * ESUB;
    const float* dv = dinv + s * NSUB;
    int st = rp[nl], en = rp[nl + 1];
    float acc = 0.f;
    for (int p = st; p < en; p++) {
        int src = cl[p];
        acc += sh[s * NSUB + src] * dv[src];
    }
    float dn = dv[nl];
    score[n] = acc * dn + sh[n] * dn * dn + ldIn(bp, 0, f32);
}

// ---------------- per-subgraph top-K via bitonic sort (set-invariant downstream) ----------------
__global__ __launch_bounds__(512) void k_topk(const float* __restrict__ score,
        int* __restrict__ perm, float* __restrict__ gate, int* __restrict__ posmap) {
    __shared__ float sv[1024];
    __shared__ int   si[1024];
    int s = blockIdx.x, t = threadIdx.x;
    for (int i = t; i < 1024; i += 512) {
        sv[i] = score[s * NSUB + i];
        si[i] = i;
        posmap[s * NSUB + i] = -1;
    }
    __syncthreads();
    for (int k = 2; k <= 1024; k <<= 1) {
        for (int j = k >> 1; j > 0; j >>= 1) {
            for (int b = t; b < 1024; b += 512) {
                int ixj = b ^ j;
                if (ixj > b) {
                    bool desc = ((b & k) == 0);
                    bool sw = desc ? (sv[b] < sv[ixj]) : (sv[b] > sv[ixj]);
                    if (sw) {
                        float tv = sv[b]; sv[b] = sv[ixj]; sv[ixj] = tv;
                        int ti = si[b]; si[b] = si[ixj]; si[ixj] = ti;
                    }
                }
            }
            __syncthreads();
        }
    }
    if (t < KSEL) {
        perm[s * KSEL + t] = si[t];
        gate[s * KSEL + t] = tanhf(sv[t]);
        posmap[s * NSUB + si[t]] = t;
    }
}

__global__ void k_deg2(const int* __restrict__ perm, const int* __restrict__ posmap,
                       const int* __restrict__ rowptr, const int* __restrict__ col,
                       float* __restrict__ dinv2) {
    int i = blockIdx.x * 256 + threadIdx.x;          // 0..32767
    int s = i >> 9;
    int n = perm[i];
    const int* rp = rowptr + s * (NSUB + 1);
    const int* cl = col + s * ESUB;
    int st = rp[n], en = rp[n + 1];
    int cnt = 0;
    for (int p = st; p < en; p++) cnt += (posmap[s * NSUB + cl[p]] >= 0) ? 1 : 0;
    dinv2[i] = rsqrtf((float)(cnt + 1));
}

__global__ void k_xpool(const float* __restrict__ x1, const int* __restrict__ perm,
                        const float* __restrict__ gate, float* __restrict__ xpool) {
    int tid = blockIdx.x * 256 + threadIdx.x;        // < 32768*128
    int i = tid >> 7, f = tid & 127;
    int s = i >> 9;
    xpool[tid] = x1[((size_t)(s * NSUB + perm[i])) * NH + f] * gate[i];
}

// max/mean over 512 rows -> [256] per subgraph; addFlag accumulates (emb1 + emb2)
__global__ void k_emb(const float* __restrict__ X, float* __restrict__ out, int addFlag) {
    int s = blockIdx.x, t = threadIdx.x;             // 256 threads
    const float* base = X + (size_t)s * KSEL * NH;
    float r;
    if (t < NH) {
        r = -INFINITY;
        for (int i = 0; i < KSEL; i++) r = fmaxf(r, base[i * NH + t]);
    } else {
        float sum = 0.f;
        for (int i = 0; i < KSEL; i++) sum += base[i * NH + (t - NH)];
        r = sum * (1.f / KSEL);
    }
    if (addFlag) out[s * 256 + t] += r; else out[s * 256 + t] = r;
}

__global__ void k_agg_pool(const float* __restrict__ hp, const float* __restrict__ dinv2,
                           const int* __restrict__ perm, const int* __restrict__ posmap,
                           const int* __restrict__ rowptr, const int* __restrict__ col,
                           const void* __restrict__ bsc, float* __restrict__ xsub,
                           const int* __restrict__ fl) {
    bool f32 = isF32(fl);
    int t = threadIdx.x;
    int i = blockIdx.x * 2 + (t >> 7);               // pooled node 0..32767
    int f = t & 127;
    int s = i >> 9;
    int n = perm[i];
    const int* rp = rowptr + s * (NSUB + 1);
    const int* cl = col + s * ESUB;
    int st = rp[n], en = rp[n + 1];
    float acc = 0.f;
    for (int p = st; p < en; p++) {
        int j = posmap[s * NSUB + cl[p]];
        if (j >= 0) acc += hp[((size_t)(s * KSEL + j)) * NH + f] * dinv2[s * KSEL + j];
    }
    float dn = dinv2[i];
    float v = acc * dn + hp[(size_t)i * NH + f] * dn * dn + ldIn(bsc, f, f32);
    xsub[(size_t)i * NH + f] = fmaxf(v, 0.f);
}

// attention degenerates (seq_len=1, softmax over 1 elem == 1): att = (se@Wv + bv)@Wo + bo
__global__ void k_attn(const float* __restrict__ subemb, const void* __restrict__ Wqkv,
                       const void* __restrict__ bqkv, const void* __restrict__ Wo,
                       const void* __restrict__ bo, float* __restrict__ att,
                       const int* __restrict__ fl) {
    bool f32 = isF32(fl);
    __shared__ float se[256], t1[256];
    int s = blockIdx.x, t = threadIdx.x;
    se[t] = subemb[s * 256 + t];
    __syncthreads();
    float acc = ldIn(bqkv, 512 + t, f32);
    for (int k = 0; k < 256; k++) acc += se[k] * ldIn(Wqkv, (size_t)k * 768 + 512 + t, f32);
    t1[t] = acc;
    __syncthreads();
    float a2 = ldIn(bo, t, f32);
    for (int k = 0; k < 256; k++) a2 += t1[k] * ldIn(Wo, (size_t)k * 256 + t, f32);
    att[s * 256 + t] = a2;
}

// scatter-add combined [x2(128) | att(256)] rows into global_emb (lives in d_out!)
__global__ __launch_bounds__(384) void k_scatter(const float* __restrict__ x2,
        const float* __restrict__ att, const int* __restrict__ orig, float* __restrict__ gemb) {
    int row = blockIdx.x;                            // s*1024 + n
    int e = threadIdx.x;                             // 0..383
    int s = row >> 10;
    int g = orig[row];
    float v = (e < NH) ? x2[(size_t)row * NH + e] : att[s * 256 + (e - NH)];
    atomicAdd(&gemb[(size_t)g * 384 + e], v);
}

// ---------------- global CSR ----------------
__global__ void k_countN(const int* __restrict__ gei, int* __restrict__ cnt) {
    int e = blockIdx.x * 256 + threadIdx.x;
    atomicAdd(&cnt[gei[EG + e]], 1);
}

__global__ __launch_bounds__(1024) void k_scanN_p1(const int* __restrict__ cnt,
        int* __restrict__ rowptr, float* __restrict__ dinvN, int* __restrict__ bsum) {
    __shared__ int sh[1024];
    int b = blockIdx.x, t = threadIdx.x;
    int v = cnt[b * 1024 + t];
    sh[t] = v;
    __syncthreads();
    for (int off = 1; off < 1024; off <<= 1) {
        int add = (t >= off) ? sh[t - off] : 0;
        __syncthreads();
        sh[t] += add;
        __syncthreads();
    }
    int incl = sh[t];
    rowptr[b * 1024 + t] = incl - v;
    dinvN[b * 1024 + t] = rsqrtf((float)(v + 1));
    if (t == 1023) bsum[b] = incl;
}

__global__ void k_scanN_p2(const int* __restrict__ bsum, int* __restrict__ boff) {
    if (threadIdx.x == 0) {
        int run = 0;
        for (int i = 0; i < 64; i++) { boff[i] = run; run += bsum[i]; }
    }
}

__global__ __launch_bounds__(1024) void k_scanN_p3(int* __restrict__ rowptr,
        int* __restrict__ cur, const int* __restrict__ boff) {
    int b = blockIdx.x, t = threadIdx.x;
    int idx = b * 1024 + t;
    int r = rowptr[idx] + boff[b];
    rowptr[idx] = r;
    cur[idx] = r;
    if (idx == 0) rowptr[NG] = EG;
}

__global__ void k_fillN(const int* __restrict__ gei, int* __restrict__ cur,
                        int* __restrict__ col) {
    int e = blockIdx.x * 256 + threadIdx.x;
    int src = gei[e], dst = gei[EG + e];
    int p = atomicAdd(&cur[dst], 1);
    col[p] = src;
}

// final GCN aggregate + bias + log_softmax over 64 classes (one wave per node) — f32 output
__global__ void k_final(const float* __restrict__ hf, const float* __restrict__ dinvN,
                        const int* __restrict__ rowptr, const int* __restrict__ col,
                        const void* __restrict__ bfb, float* __restrict__ out,
                        const int* __restrict__ fl) {
    bool f32 = isF32(fl);
    int t = threadIdx.x;
    int n = blockIdx.x * 4 + (t >> 6);
    int f = t & 63;
    int st = rowptr[n], en = rowptr[n + 1];
    float acc = 0.f;
    for (int p = st; p < en; p++) {
        int src = col[p];
        acc += hf[(size_t)src * 64 + f] * dinvN[src];
    }
    float dn = dinvN[n];
    float x = acc * dn + hf[(size_t)n * 64 + f] * dn * dn + ldIn(bfb, f, f32);
    float m = x;
    for (int o = 32; o > 0; o >>= 1) m = fmaxf(m, __shfl_xor(m, o, 64));
    float e = expf(x - m);
    float ssum = e;
    for (int o = 32; o > 0; o >>= 1) ssum += __shfl_xor(ssum, o, 64);
    out[(size_t)n * 64 + f] = x - m - logf(ssum);
}

// ---------------- host ----------------
extern "C" void kernel_launch(void* const* d_in, const int* in_sizes, int n_in,
                              void* d_out, int out_size, void* d_ws, size_t ws_size,
                              hipStream_t stream) {
    const void* sub_x = d_in[0];
    const int*  sei   = (const int*)d_in[1];
    const int*  sorig = (const int*)d_in[2];
    const int*  gei   = (const int*)d_in[3];
    const void *W1 = d_in[4],  *b1  = d_in[5];
    const void *W2 = d_in[6],  *b2  = d_in[7];
    const void *Wp = d_in[8],  *bp  = d_in[9];
    const void *Wsc = d_in[10], *bsc = d_in[11];
    const void *Wqkv = d_in[12], *bqkv = d_in[13];
    const void *Wo = d_in[14], *bo  = d_in[15];
    const void *Wf = d_in[16], *bfb = d_in[17];

    // OUTPUTS ARE FLOAT32 (reference output dtype). out0 = logits log-softmax [NG,64];
    // out1 = global_emb [NG,384] — gemb lives directly in d_out (saves a 100 MB cast pass).
    float* out0 = (float*)d_out;
    float* gemb = (float*)d_out + (size_t)NG * 64;

    char* w = (char*)d_ws;
    size_t off = 0;
    auto alloc = [&](size_t nbytes) -> void* {
        off = (off + 255) & ~(size_t)255;
        void* p = w + off;
        off += nbytes;
        return p;
    };
    // smalls first
    int*   fl      = (int*)alloc(2 * 4);
    int*   bsum    = (int*)alloc(64 * 4);
    int*   boff    = (int*)alloc(64 * 4);
    float* dinv    = (float*)alloc((size_t)NG * 4);        // alias: dinvN
    float* scoreh  = (float*)alloc((size_t)NG * 4);
    float* score   = (float*)alloc((size_t)NG * 4);
    float* gate    = (float*)alloc((size_t)S * KSEL * 4);
    float* dinv2   = (float*)alloc((size_t)S * KSEL * 4);
    float* subemb  = (float*)alloc((size_t)S * 256 * 4);
    float* att     = (float*)alloc((size_t)S * 256 * 4);
    int*   perm    = (int*)alloc((size_t)S * KSEL * 4);
    int*   posmap  = (int*)alloc((size_t)NG * 4);
    int*   cnt_sub = (int*)alloc((size_t)NG * 4);          // alias: cntN
    int*   cur_sub = (int*)alloc((size_t)NG * 4);          // alias: curN
    int*   rowptr_s= (int*)alloc((size_t)(NG + 64) * 4);   // alias: rowptrN
    int*   col_sub = (int*)alloc((size_t)EG * 4);          // alias: colN
    float* x1      = (float*)alloc((size_t)NG * NH * 4);   // alias: xsub (x1 dead after k_xpool)
    float* x2      = (float*)alloc((size_t)NG * NH * 4);
    float* hbuf    = (float*)alloc((size_t)NG * NH * 4);   // alias: hf (dead after k_agg_pool)
    float* xpool   = (float*)alloc((size_t)S * KSEL * NH * 4);
    // aliases
    float* xsub    = x1;
    float* hf      = hbuf;
    float* dinvN   = dinv;
    int*   cntN    = cnt_sub;
    int*   curN    = cur_sub;
    int*   rowptrN = rowptr_s;
    int*   colN    = col_sub;

    hipMemsetAsync(fl, 0, 8, stream);
    hipMemsetAsync(cnt_sub, 0, (size_t)NG * 4, stream);
    hipMemsetAsync(gemb, 0, (size_t)NG * 384 * 4, stream);   // d_out is 0xAA-poisoned pre-launch

    // input dtype probe (f32 vs bf16) — f32 confirmed empirically, probe kept as insurance
    k_detect<<<8192, 256, 0, stream>>>((const unsigned short*)sub_x, fl);

    // per-subgraph CSR
    k_count_sub<<<4096, 256, 0, stream>>>(sei, cnt_sub);
    k_scan_sub<<<S, 1024, 0, stream>>>(cnt_sub, rowptr_s, cur_sub, dinv);
    k_fill_sub<<<4096, 256, 0, stream>>>(sei, cur_sub, col_sub);

    // GCN1
    k_matmul<128, 128><<<dim3(NG / 64, 2), 256, 0, stream>>>(sub_x, W1, hbuf, fl, 1);
    k_agg128<<<NG / 2, 256, 0, stream>>>(hbuf, dinv, rowptr_s, col_sub, b1, x1, fl);
    // GCN2
    k_matmul<128, 128><<<dim3(NG / 64, 2), 256, 0, stream>>>(x1, W2, hbuf, fl, 0);
    k_agg128<<<NG / 2, 256, 0, stream>>>(hbuf, dinv, rowptr_s, col_sub, b2, x2, fl);
    // scorer GCN + top-k pooling
    k_score_h<<<NG / 4, 256, 0, stream>>>(x1, Wp, scoreh, fl);
    k_score_agg<<<NG / 256, 256, 0, stream>>>(scoreh, dinv, rowptr_s, col_sub, bp, score, fl);
    k_topk<<<S, 512, 0, stream>>>(score, perm, gate, posmap);
    k_deg2<<<(S * KSEL) / 256, 256, 0, stream>>>(perm, posmap, rowptr_s, col_sub, dinv2);
    k_xpool<<<(S * KSEL * NH) / 256, 256, 0, stream>>>(x1, perm, gate, xpool);   // last x1 read
    k_emb<<<S, 256, 0, stream>>>(xpool, subemb, 0);
    // pooled GCN (xsub aliases x1)
    k_matmul<128, 128><<<dim3((S * KSEL) / 64, 2), 256, 0, stream>>>(xpool, Wsc, hbuf, fl, 0);
    k_agg_pool<<<(S * KSEL) / 2, 256, 0, stream>>>(hbuf, dinv2, perm, posmap, rowptr_s, col_sub, bsc, xsub, fl);
    k_emb<<<S, 256, 0, stream>>>(xsub, subemb, 1);
    // attention (degenerate) -> att
    k_attn<<<S, 256, 0, stream>>>(subemb, Wqkv, bqkv, Wo, bo, att, fl);
    // scatter into global embedding (direct into d_out region)
    k_scatter<<<NG, 384, 0, stream>>>(x2, att, sorig, gemb);

    // global CSR (aliases; per-subgraph CSR dead)
    hipMemsetAsync(cntN, 0, (size_t)NG * 4, stream);
    k_countN<<<EG / 256, 256, 0, stream>>>(gei, cntN);
    k_scanN_p1<<<NG / 1024, 1024, 0, stream>>>(cntN, rowptrN, dinvN, bsum);
    k_scanN_p2<<<1, 64, 0, stream>>>(bsum, boff);
    k_scanN_p3<<<NG / 1024, 1024, 0, stream>>>(rowptrN, curN, boff);
    k_fillN<<<EG / 256, 256, 0, stream>>>(gei, curN, colN);

    // final GCN + log_softmax (f32 out)
    k_matmul<384, 64><<<dim3(NG / 64, 1), 256, 0, stream>>>(gemb, Wf, hf, fl, 0);
    k_final<<<NG / 4, 256, 0, stream>>>(hf, dinvN, rowptrN, colN, bfb, out0, fl);

    (void)in_sizes; (void)n_in; (void)out_size; (void)ws_size;
}

// Round 5
// 886.812 us; speedup vs baseline: 1.6951x; 1.6951x over previous
//
#include <hip/hip_runtime.h>
#include <math.h>

#define S     64
#define NSUB  1024
#define ESUB  16384
#define NG    65536
#define EG    1048576
#define NH    128
#define KSEL  512

// ---------------- CSR build (per-subgraph) ----------------
__global__ void k_count_sub(const int* __restrict__ sei, int* __restrict__ cnt) {
    int e = blockIdx.x * 256 + threadIdx.x;          // < S*ESUB
    int s = e >> 14, el = e & (ESUB - 1);
    int dst = sei[s * 2 * ESUB + ESUB + el];
    atomicAdd(&cnt[s * NSUB + dst], 1);
}

__global__ __launch_bounds__(1024) void k_scan_sub(const int* __restrict__ cnt,
        int* __restrict__ rowptr, int* __restrict__ cur, float* __restrict__ dinv) {
    __shared__ int sh[1024];
    int s = blockIdx.x, t = threadIdx.x;
    int v = cnt[s * NSUB + t];
    sh[t] = v;
    __syncthreads();
    for (int off = 1; off < 1024; off <<= 1) {
        int add = (t >= off) ? sh[t - off] : 0;
        __syncthreads();
        sh[t] += add;
        __syncthreads();
    }
    int incl = sh[t];
    rowptr[s * (NSUB + 1) + t] = incl - v;
    cur[s * NSUB + t] = incl - v;
    dinv[s * NSUB + t] = rsqrtf((float)(v + 1));     // deg = indeg + 1 (self loop)
    if (t == 1023) rowptr[s * (NSUB + 1) + NSUB] = incl;
}

__global__ void k_fill_sub(const int* __restrict__ sei, int* __restrict__ cur,
                           int* __restrict__ col) {
    int e = blockIdx.x * 256 + threadIdx.x;
    int s = e >> 14, el = e & (ESUB - 1);
    int src = sei[s * 2 * ESUB + el];
    int dst = sei[s * 2 * ESUB + ESUB + el];
    int p = atomicAdd(&cur[s * NSUB + dst], 1);
    col[s * ESUB + p] = src;
}

// ---------------- tiled matmul: Y[M,NCOL] = X[M,KDIM] @ W[KDIM,NCOL] (all f32) --------
template<int KDIM, int NCOL>
__global__ __launch_bounds__(256) void k_matmul(const float* __restrict__ X,
        const float* __restrict__ W, float* __restrict__ Y) {
    __shared__ float As[16][72];   // [k][row], pad 72 (288B, 16B-aligned rows)
    __shared__ float Bs[16][72];   // [k][col]
    int t = threadIdx.x;
    int row0 = blockIdx.x * 64;
    int col0 = blockIdx.y * 64;
    int tr = t >> 4, tc = t & 15;
    float acc[4][4] = {};
    for (int k0 = 0; k0 < KDIM; k0 += 16) {
        {   // stage A: 64 rows x 16 k = 256 float4
            int r = t >> 2, kq = t & 3;
            float4 v = *(const float4*)&X[(size_t)(row0 + r) * KDIM + k0 + kq * 4];
            As[kq * 4 + 0][r] = v.x; As[kq * 4 + 1][r] = v.y;
            As[kq * 4 + 2][r] = v.z; As[kq * 4 + 3][r] = v.w;
        }
        {   // stage B: 16 k x 16 float4
            int k = t >> 4, cq = t & 15;
            float4 v = *(const float4*)&W[(size_t)(k0 + k) * NCOL + col0 + cq * 4];
            *(float4*)&Bs[k][cq * 4] = v;
        }
        __syncthreads();
        #pragma unroll
        for (int k = 0; k < 16; k++) {
            float a0 = As[k][tr * 4 + 0], a1 = As[k][tr * 4 + 1];
            float a2 = As[k][tr * 4 + 2], a3 = As[k][tr * 4 + 3];
            float b0 = Bs[k][tc * 4 + 0], b1 = Bs[k][tc * 4 + 1];
            float b2 = Bs[k][tc * 4 + 2], b3 = Bs[k][tc * 4 + 3];
            acc[0][0] += a0 * b0; acc[0][1] += a0 * b1; acc[0][2] += a0 * b2; acc[0][3] += a0 * b3;
            acc[1][0] += a1 * b0; acc[1][1] += a1 * b1; acc[1][2] += a1 * b2; acc[1][3] += a1 * b3;
            acc[2][0] += a2 * b0; acc[2][1] += a2 * b1; acc[2][2] += a2 * b2; acc[2][3] += a2 * b3;
            acc[3][0] += a3 * b0; acc[3][1] += a3 * b1; acc[3][2] += a3 * b2; acc[3][3] += a3 * b3;
        }
        __syncthreads();
    }
    #pragma unroll
    for (int i = 0; i < 4; i++) {
        float4 v = { acc[i][0], acc[i][1], acc[i][2], acc[i][3] };
        *(float4*)&Y[(size_t)(row0 + tr * 4 + i) * NCOL + col0 + tc * 4] = v;
    }
}

// ------- GCN aggregate (128 feats) + self + bias + relu; float4 + XCD swizzle --------
__global__ __launch_bounds__(256) void k_agg128(const float4* __restrict__ h,
        const float* __restrict__ dinv, const int* __restrict__ rowptr,
        const int* __restrict__ col, const float* __restrict__ bias,
        float4* __restrict__ out) {
    int b = blockIdx.x;                  // 8192 blocks
    int s = b & 63;                      // subgraph -> fixed XCD (b%8 == s%8): L2 locality
    int chunk = b >> 6;                  // 128 chunks of 8 nodes
    int t = threadIdx.x;
    int nl = chunk * 8 + (t >> 5);       // local node
    int f4 = t & 31;                     // float4 lane (32 x 4 = 128 feats)
    const int* rp = rowptr + s * (NSUB + 1);
    int st = rp[nl], en = rp[nl + 1];
    const int* cl = col + s * ESUB;
    const float* dv = dinv + s * NSUB;
    float4 acc = {0.f, 0.f, 0.f, 0.f};
    for (int p = st; p < en; p++) {
        int src = cl[p];
        float d = dv[src];
        float4 hv = h[((size_t)(s * NSUB + src)) * 32 + f4];
        acc.x += hv.x * d; acc.y += hv.y * d; acc.z += hv.z * d; acc.w += hv.w * d;
    }
    size_t node = (size_t)s * NSUB + nl;
    float dn = dv[nl];
    float dn2 = dn * dn;
    float4 hs = h[node * 32 + f4];
    float4 bb = ((const float4*)bias)[f4];
    float4 r;
    r.x = fmaxf(acc.x * dn + hs.x * dn2 + bb.x, 0.f);
    r.y = fmaxf(acc.y * dn + hs.y * dn2 + bb.y, 0.f);
    r.z = fmaxf(acc.z * dn + hs.z * dn2 + bb.z, 0.f);
    r.w = fmaxf(acc.w * dn + hs.w * dn2 + bb.w, 0.f);
    out[node * 32 + f4] = r;
}

// ---------------- scorer: h = x1 @ Wp ----------------
__global__ void k_score_h(const float* __restrict__ x1, const float* __restrict__ Wp,
                          float* __restrict__ sh) {
    int t = threadIdx.x;
    int n = blockIdx.x * 4 + (t >> 6);
    int l = t & 63;
    float p = x1[(size_t)n * NH + l] * Wp[l] + x1[(size_t)n * NH + 64 + l] * Wp[64 + l];
    for (int o = 32; o > 0; o >>= 1) p += __shfl_xor(p, o, 64);
    if (l == 0) sh[n] = p;
}

__global__ void k_score_agg(const float* __restrict__ sh, const float* __restrict__ dinv,
                            const int* __restrict__ rowptr, const int* __restrict__ col,
                            const float* __restrict__ bp, float* __restrict__ score) {
    int n = blockIdx.x * 256 + threadIdx.x;          // 0..65535
    int s = n >> 10, nl = n & (NSUB - 1);
    const int* rp = rowptr + s * (NSUB + 1);
    const int* cl = col + s * ESUB;
    const float* dv = dinv + s * NSUB;
    int st = rp[nl], en = rp[nl + 1];
    float acc = 0.f;
    for (int p = st; p < en; p++) {
        int src = cl[p];
        acc += sh[s * NSUB + src] * dv[src];
    }
    float dn = dv[nl];
    score[n] = acc * dn + sh[n] * dn * dn + bp[0];
}

// ---------------- per-subgraph top-K via bitonic sort (set-invariant downstream) -----
__global__ __launch_bounds__(512) void k_topk(const float* __restrict__ score,
        int* __restrict__ perm, float* __restrict__ gate, int* __restrict__ posmap) {
    __shared__ float sv[1024];
    __shared__ int   si[1024];
    int s = blockIdx.x, t = threadIdx.x;
    for (int i = t; i < 1024; i += 512) {
        sv[i] = score[s * NSUB + i];
        si[i] = i;
        posmap[s * NSUB + i] = -1;
    }
    __syncthreads();
    for (int k = 2; k <= 1024; k <<= 1) {
        for (int j = k >> 1; j > 0; j >>= 1) {
            for (int b = t; b < 1024; b += 512) {
                int ixj = b ^ j;
                if (ixj > b) {
                    bool desc = ((b & k) == 0);
                    bool sw = desc ? (sv[b] < sv[ixj]) : (sv[b] > sv[ixj]);
                    if (sw) {
                        float tv = sv[b]; sv[b] = sv[ixj]; sv[ixj] = tv;
                        int ti = si[b]; si[b] = si[ixj]; si[ixj] = ti;
                    }
                }
            }
            __syncthreads();
        }
    }
    if (t < KSEL) {
        perm[s * KSEL + t] = si[t];
        gate[s * KSEL + t] = tanhf(sv[t]);
        posmap[s * NSUB + si[t]] = t;
    }
}

__global__ void k_deg2(const int* __restrict__ perm, const int* __restrict__ posmap,
                       const int* __restrict__ rowptr, const int* __restrict__ col,
                       float* __restrict__ dinv2) {
    int i = blockIdx.x * 256 + threadIdx.x;          // 0..32767
    int s = i >> 9;
    int n = perm[i];
    const int* rp = rowptr + s * (NSUB + 1);
    const int* cl = col + s * ESUB;
    int st = rp[n], en = rp[n + 1];
    int cnt = 0;
    for (int p = st; p < en; p++) cnt += (posmap[s * NSUB + cl[p]] >= 0) ? 1 : 0;
    dinv2[i] = rsqrtf((float)(cnt + 1));
}

__global__ void k_xpool(const float4* __restrict__ x1, const int* __restrict__ perm,
                        const float* __restrict__ gate, float4* __restrict__ xpool) {
    int tid = blockIdx.x * 256 + threadIdx.x;        // < 32768*32
    int i = tid >> 5, f4 = tid & 31;
    int s = i >> 9;
    float g = gate[i];
    float4 v = x1[((size_t)(s * NSUB + perm[i])) * 32 + f4];
    v.x *= g; v.y *= g; v.z *= g; v.w *= g;
    xpool[tid] = v;
}

// max/mean over 512 rows -> [256] per subgraph; 4-sliced; addFlag accumulates
__global__ __launch_bounds__(1024) void k_emb(const float* __restrict__ X,
        float* __restrict__ out, int addFlag) {
    __shared__ float red[4][256];
    int s = blockIdx.x, t = threadIdx.x;
    int sl = t >> 8, f = t & 255;
    const float* base = X + (size_t)s * KSEL * NH;
    float r;
    if (f < NH) {
        r = -INFINITY;
        for (int i = sl * 128; i < sl * 128 + 128; i++) r = fmaxf(r, base[i * NH + f]);
    } else {
        r = 0.f;
        for (int i = sl * 128; i < sl * 128 + 128; i++) r += base[i * NH + (f - NH)];
    }
    red[sl][f] = r;
    __syncthreads();
    if (sl == 0) {
        float a = red[0][f], b = red[1][f], c = red[2][f], d = red[3][f];
        float v = (f < NH) ? fmaxf(fmaxf(a, b), fmaxf(c, d)) : (a + b + c + d) * (1.f / KSEL);
        out[s * 256 + f] = addFlag ? out[s * 256 + f] + v : v;
    }
}

// pooled GCN aggregate; float4 + XCD swizzle (512 nodes/subgraph -> 64 chunks of 8)
__global__ __launch_bounds__(256) void k_agg_pool(const float4* __restrict__ hp,
        const float* __restrict__ dinv2, const int* __restrict__ perm,
        const int* __restrict__ posmap, const int* __restrict__ rowptr,
        const int* __restrict__ col, const float* __restrict__ bsc,
        float4* __restrict__ xsub) {
    int b = blockIdx.x;                  // 4096 blocks
    int s = b & 63;
    int chunk = b >> 6;                  // 64 chunks of 8 pooled nodes
    int t = threadIdx.x;
    int il = chunk * 8 + (t >> 5);       // pooled-local 0..511
    int f4 = t & 31;
    int i = s * KSEL + il;
    int n = perm[i];
    const int* rp = rowptr + s * (NSUB + 1);
    const int* cl = col + s * ESUB;
    int st = rp[n], en = rp[n + 1];
    float4 acc = {0.f, 0.f, 0.f, 0.f};
    for (int p = st; p < en; p++) {
        int j = posmap[s * NSUB + cl[p]];
        if (j >= 0) {
            float d = dinv2[s * KSEL + j];
            float4 hv = hp[((size_t)(s * KSEL + j)) * 32 + f4];
            acc.x += hv.x * d; acc.y += hv.y * d; acc.z += hv.z * d; acc.w += hv.w * d;
        }
    }
    float dn = dinv2[i];
    float dn2 = dn * dn;
    float4 hs = hp[(size_t)i * 32 + f4];
    float4 bb = ((const float4*)bsc)[f4];
    float4 r;
    r.x = fmaxf(acc.x * dn + hs.x * dn2 + bb.x, 0.f);
    r.y = fmaxf(acc.y * dn + hs.y * dn2 + bb.y, 0.f);
    r.z = fmaxf(acc.z * dn + hs.z * dn2 + bb.z, 0.f);
    r.w = fmaxf(acc.w * dn + hs.w * dn2 + bb.w, 0.f);
    xsub[(size_t)i * 32 + f4] = r;
}

// attention degenerates (seq_len=1): att = (se@Wv + bv)@Wo + bo
__global__ void k_attn(const float* __restrict__ subemb, const float* __restrict__ Wqkv,
                       const float* __restrict__ bqkv, const float* __restrict__ Wo,
                       const float* __restrict__ bo, float* __restrict__ att) {
    __shared__ float se[256], t1[256];
    int s = blockIdx.x, t = threadIdx.x;
    se[t] = subemb[s * 256 + t];
    __syncthreads();
    float acc = bqkv[512 + t];
    for (int k = 0; k < 256; k++) acc += se[k] * Wqkv[(size_t)k * 768 + 512 + t];
    t1[t] = acc;
    __syncthreads();
    float a2 = bo[t];
    for (int k = 0; k < 256; k++) a2 += t1[k] * Wo[(size_t)k * 256 + t];
    att[s * 256 + t] = a2;
}

// scatter-add combined [x2(128) | att(256)] rows into global_emb (lives in d_out)
__global__ __launch_bounds__(384) void k_scatter(const float* __restrict__ x2,
        const float* __restrict__ att, const int* __restrict__ orig, float* __restrict__ gemb) {
    int row = blockIdx.x;                            // s*1024 + n
    int e = threadIdx.x;                             // 0..383
    int s = row >> 10;
    int g = orig[row];
    float v = (e < NH) ? x2[(size_t)row * NH + e] : att[s * 256 + (e - NH)];
    atomicAdd(&gemb[(size_t)g * 384 + e], v);
}

// ---------------- global CSR ----------------
__global__ void k_countN(const int* __restrict__ gei, int* __restrict__ cnt) {
    int e = blockIdx.x * 256 + threadIdx.x;
    atomicAdd(&cnt[gei[EG + e]], 1);
}

__global__ __launch_bounds__(1024) void k_scanN_p1(const int* __restrict__ cnt,
        int* __restrict__ rowptr, float* __restrict__ dinvN, int* __restrict__ bsum) {
    __shared__ int sh[1024];
    int b = blockIdx.x, t = threadIdx.x;
    int v = cnt[b * 1024 + t];
    sh[t] = v;
    __syncthreads();
    for (int off = 1; off < 1024; off <<= 1) {
        int add = (t >= off) ? sh[t - off] : 0;
        __syncthreads();
        sh[t] += add;
        __syncthreads();
    }
    int incl = sh[t];
    rowptr[b * 1024 + t] = incl - v;
    dinvN[b * 1024 + t] = rsqrtf((float)(v + 1));
    if (t == 1023) bsum[b] = incl;
}

__global__ void k_scanN_p2(const int* __restrict__ bsum, int* __restrict__ boff) {
    if (threadIdx.x == 0) {
        int run = 0;
        for (int i = 0; i < 64; i++) { boff[i] = run; run += bsum[i]; }
    }
}

__global__ __launch_bounds__(1024) void k_scanN_p3(int* __restrict__ rowptr,
        int* __restrict__ cur, const int* __restrict__ boff) {
    int b = blockIdx.x, t = threadIdx.x;
    int idx = b * 1024 + t;
    int r = rowptr[idx] + boff[b];
    rowptr[idx] = r;
    cur[idx] = r;
    if (idx == 0) rowptr[NG] = EG;
}

__global__ void k_fillN(const int* __restrict__ gei, int* __restrict__ cur,
                        int* __restrict__ col) {
    int e = blockIdx.x * 256 + threadIdx.x;
    int src = gei[e], dst = gei[EG + e];
    int p = atomicAdd(&cur[dst], 1);
    col[p] = src;
}

// final GCN aggregate + bias + log_softmax (64 classes = 16 float4 lanes per node)
__global__ __launch_bounds__(256) void k_final(const float4* __restrict__ hf,
        const float* __restrict__ dinvN, const int* __restrict__ rowptr,
        const int* __restrict__ col, const float* __restrict__ bfb,
        float4* __restrict__ out) {
    int t = threadIdx.x;
    int n = blockIdx.x * 16 + (t >> 4);              // 16 nodes per block
    int f4 = t & 15;                                 // 16 float4 = 64 classes
    int st = rowptr[n], en = rowptr[n + 1];
    float4 acc = {0.f, 0.f, 0.f, 0.f};
    for (int p = st; p < en; p++) {
        int src = col[p];
        float d = dinvN[src];
        float4 hv = hf[(size_t)src * 16 + f4];
        acc.x += hv.x * d; acc.y += hv.y * d; acc.z += hv.z * d; acc.w += hv.w * d;
    }
    float dn = dinvN[n];
    float dn2 = dn * dn;
    float4 hs = hf[(size_t)n * 16 + f4];
    float4 bb = ((const float4*)bfb)[f4];
    float4 x;
    x.x = acc.x * dn + hs.x * dn2 + bb.x;
    x.y = acc.y * dn + hs.y * dn2 + bb.y;
    x.z = acc.z * dn + hs.z * dn2 + bb.z;
    x.w = acc.w * dn + hs.w * dn2 + bb.w;
    float m = fmaxf(fmaxf(x.x, x.y), fmaxf(x.z, x.w));
    for (int o = 1; o < 16; o <<= 1) m = fmaxf(m, __shfl_xor(m, o, 64));
    float ssum = expf(x.x - m) + expf(x.y - m) + expf(x.z - m) + expf(x.w - m);
    for (int o = 1; o < 16; o <<= 1) ssum += __shfl_xor(ssum, o, 64);
    float lz = m + logf(ssum);
    float4 r = { x.x - lz, x.y - lz, x.z - lz, x.w - lz };
    out[(size_t)n * 16 + f4] = r;
}

// ---------------- host ----------------
extern "C" void kernel_launch(void* const* d_in, const int* in_sizes, int n_in,
                              void* d_out, int out_size, void* d_ws, size_t ws_size,
                              hipStream_t stream) {
    const float* sub_x = (const float*)d_in[0];
    const int*   sei   = (const int*)d_in[1];
    const int*   sorig = (const int*)d_in[2];
    const int*   gei   = (const int*)d_in[3];
    const float *W1 = (const float*)d_in[4],  *b1  = (const float*)d_in[5];
    const float *W2 = (const float*)d_in[6],  *b2  = (const float*)d_in[7];
    const float *Wp = (const float*)d_in[8],  *bp  = (const float*)d_in[9];
    const float *Wsc = (const float*)d_in[10], *bsc = (const float*)d_in[11];
    const float *Wqkv = (const float*)d_in[12], *bqkv = (const float*)d_in[13];
    const float *Wo = (const float*)d_in[14], *bo  = (const float*)d_in[15];
    const float *Wf = (const float*)d_in[16], *bfb = (const float*)d_in[17];

    float* out0 = (float*)d_out;                      // log-softmax [NG,64]
    float* gemb = (float*)d_out + (size_t)NG * 64;    // global_emb [NG,384] in-place

    char* w = (char*)d_ws;
    size_t off = 0;
    auto alloc = [&](size_t nbytes) -> void* {
        off = (off + 255) & ~(size_t)255;
        void* p = w + off;
        off += nbytes;
        return p;
    };
    int*   bsum    = (int*)alloc(64 * 4);
    int*   boff    = (int*)alloc(64 * 4);
    float* dinv    = (float*)alloc((size_t)NG * 4);        // alias: dinvN
    float* scoreh  = (float*)alloc((size_t)NG * 4);
    float* score   = (float*)alloc((size_t)NG * 4);
    float* gate    = (float*)alloc((size_t)S * KSEL * 4);
    float* dinv2   = (float*)alloc((size_t)S * KSEL * 4);
    float* subemb  = (float*)alloc((size_t)S * 256 * 4);
    float* att     = (float*)alloc((size_t)S * 256 * 4);
    int*   perm    = (int*)alloc((size_t)S * KSEL * 4);
    int*   posmap  = (int*)alloc((size_t)NG * 4);
    int*   cnt_sub = (int*)alloc((size_t)NG * 4);          // alias: cntN
    int*   cur_sub = (int*)alloc((size_t)NG * 4);          // alias: curN
    int*   rowptr_s= (int*)alloc((size_t)(NG + 64) * 4);   // alias: rowptrN
    int*   col_sub = (int*)alloc((size_t)EG * 4);          // alias: colN
    float* x1      = (float*)alloc((size_t)NG * NH * 4);   // alias: xsub
    float* x2      = (float*)alloc((size_t)NG * NH * 4);
    float* hbuf    = (float*)alloc((size_t)NG * NH * 4);   // alias: hf
    float* xpool   = (float*)alloc((size_t)S * KSEL * NH * 4);
    float* xsub    = x1;
    float* hf      = hbuf;
    float* dinvN   = dinv;
    int*   cntN    = cnt_sub;
    int*   curN    = cur_sub;
    int*   rowptrN = rowptr_s;
    int*   colN    = col_sub;

    hipMemsetAsync(cnt_sub, 0, (size_t)NG * 4, stream);
    hipMemsetAsync(gemb, 0, (size_t)NG * 384 * 4, stream);

    // per-subgraph CSR
    k_count_sub<<<4096, 256, 0, stream>>>(sei, cnt_sub);
    k_scan_sub<<<S, 1024, 0, stream>>>(cnt_sub, rowptr_s, cur_sub, dinv);
    k_fill_sub<<<4096, 256, 0, stream>>>(sei, cur_sub, col_sub);

    // GCN1
    k_matmul<128, 128><<<dim3(NG / 64, 2), 256, 0, stream>>>(sub_x, W1, hbuf);
    k_agg128<<<8192, 256, 0, stream>>>((const float4*)hbuf, dinv, rowptr_s, col_sub, b1, (float4*)x1);
    // GCN2
    k_matmul<128, 128><<<dim3(NG / 64, 2), 256, 0, stream>>>(x1, W2, hbuf);
    k_agg128<<<8192, 256, 0, stream>>>((const float4*)hbuf, dinv, rowptr_s, col_sub, b2, (float4*)x2);
    // scorer GCN + top-k pooling
    k_score_h<<<NG / 4, 256, 0, stream>>>(x1, Wp, scoreh);
    k_score_agg<<<NG / 256, 256, 0, stream>>>(scoreh, dinv, rowptr_s, col_sub, bp, score);
    k_topk<<<S, 512, 0, stream>>>(score, perm, gate, posmap);
    k_deg2<<<(S * KSEL) / 256, 256, 0, stream>>>(perm, posmap, rowptr_s, col_sub, dinv2);
    k_xpool<<<(S * KSEL * 32) / 256, 256, 0, stream>>>((const float4*)x1, perm, gate, (float4*)xpool);
    k_emb<<<S, 1024, 0, stream>>>(xpool, subemb, 0);
    // pooled GCN (xsub aliases x1)
    k_matmul<128, 128><<<dim3((S * KSEL) / 64, 2), 256, 0, stream>>>(xpool, Wsc, hbuf);
    k_agg_pool<<<4096, 256, 0, stream>>>((const float4*)hbuf, dinv2, perm, posmap, rowptr_s, col_sub, bsc, (float4*)xsub);
    k_emb<<<S, 1024, 0, stream>>>(xsub, subemb, 1);
    // attention (degenerate) -> att
    k_attn<<<S, 256, 0, stream>>>(subemb, Wqkv, bqkv, Wo, bo, att);
    // scatter into global embedding (direct into d_out region)
    k_scatter<<<NG, 384, 0, stream>>>(x2, att, sorig, gemb);

    // global CSR (aliases; per-subgraph CSR dead)
    hipMemsetAsync(cntN, 0, (size_t)NG * 4, stream);
    k_countN<<<EG / 256, 256, 0, stream>>>(gei, cntN);
    k_scanN_p1<<<NG / 1024, 1024, 0, stream>>>(cntN, rowptrN, dinvN, bsum);
    k_scanN_p2<<<1, 64, 0, stream>>>(bsum, boff);
    k_scanN_p3<<<NG / 1024, 1024, 0, stream>>>(rowptrN, curN, boff);
    k_fillN<<<EG / 256, 256, 0, stream>>>(gei, curN, colN);

    // final GCN + log_softmax (f32 out)
    k_matmul<384, 64><<<dim3(NG / 64, 1), 256, 0, stream>>>(gemb, Wf, hf);
    k_final<<<NG / 16, 256, 0, stream>>>((const float4*)hf, dinvN, rowptrN, colN, bfb, (float4*)out0);

    (void)in_sizes; (void)n_in; (void)out_size; (void)ws_size;
}